// Round 6
// baseline (140.101 us; speedup 1.0000x reference)
//
#include <hip/hip_runtime.h>
#include <hip/hip_bf16.h>
#include <math.h>

// Problem constants
namespace {
constexpr int kB  = 64;
constexpr int kNi = 2048;
constexpr int kDi = 8;
constexpr int kNo = 32;
constexpr int kDo = 16;

constexpr int kThreads    = 1024;                // 16 waves
constexpr int kNBlocks    = 256;                 // grid = 1 block/CU
constexpr int kNPerBlock  = kNi / kNBlocks;      // 8 n per block
constexpr int kSeg        = kNo * kDo;           // 512 od elements
// W per n as bf16: 4096 bf16 = 8192 B = 512 x 16B chunks
constexpr int kChunksPerN = 512;
}

__device__ __forceinline__ unsigned pack_bf16(float lo, float hi) {
    union { __hip_bfloat162 h; unsigned u; } v;
    v.h = __float22bfloat162_rn(make_float2(lo, hi));
    return v.u;
}
__device__ __forceinline__ int swz(int c) { return c ^ ((c >> 4) & 7); }

// ---------------------------------------------------------------------------
// Pass kernel. Block owns 8 n's; W staged ONCE as packed bf16 (64 KB LDS,
// one barrier). 16 waves; wave wv owns b in [wv*4, wv*4+4).
// lane -> (o = lane&31, half = lane>>5 covering d in [half*8, half*8+8)).
// Per (n, dd): one ds_read_b128 (8 bf16 = W[n,o,half*8+dd,0..8)), swizzled so
// the 64 lanes tile all 8 16B-slots (the 1024B/instr LDS floor).
// x loads wave-uniform -> SGPR broadcast; W reads pipelined 3 deep.
// c = softmax_o(vsum . x_hat); PASS==0 uniform (1/32 applied in finish).
// __launch_bounds__(1024,1): 16 waves/CU -> 4 waves/SIMD, 128-VGPR cap
// (empirical: arg2 acts as min blocks/CU on this toolchain).
// ---------------------------------------------------------------------------
template<int PASS>
__global__ __launch_bounds__(kThreads, 1)
void caps_pass(const float* __restrict__ xg, const float* __restrict__ Wg,
               const float* __restrict__ vsum, __hip_bfloat16* __restrict__ partial)
{
    __shared__ int4 lds[kNPerBlock * kChunksPerN];   // 65536 B

    const int tid    = threadIdx.x;
    const int nchunk = blockIdx.x;                     // 0..255
    const int wv     = __builtin_amdgcn_readfirstlane(tid >> 6);  // 0..15
    const int lane   = tid & 63;
    const int o      = lane & 31;
    const int half   = lane >> 5;
    const int bbase  = wv * 4;                         // 4 b's per wave

    // ---- stage all 8 W tiles as packed bf16 (64 KB), swizzled ----
    {
        const float4* src = reinterpret_cast<const float4*>(Wg)
                          + (size_t)nchunk * (kNPerBlock * kChunksPerN * 2);
#pragma unroll
        for (int k = 0; k < (kNPerBlock * kChunksPerN) / kThreads; ++k) {  // 4
            int c = k * kThreads + tid;
            float4 a = src[2 * c], b = src[2 * c + 1];
            int4 u;
            u.x = pack_bf16(a.x, a.y);
            u.y = pack_bf16(a.z, a.w);
            u.z = pack_bf16(b.x, b.y);
            u.w = pack_bf16(b.z, b.w);
            lds[swz(c)] = u;
        }
    }

    float vs[4][8];
    float sacc[4][8];
#pragma unroll
    for (int b2 = 0; b2 < 4; ++b2) {
#pragma unroll
        for (int j = 0; j < 8; ++j) sacc[b2][j] = 0.0f;
        if (PASS > 0) {
            const float4* vp = reinterpret_cast<const float4*>(
                vsum + (size_t)(bbase + b2) * kSeg + o * kDo + half * 8);
            float4 a = vp[0], b4 = vp[1];
            vs[b2][0] = a.x;  vs[b2][1] = a.y;  vs[b2][2] = a.z;  vs[b2][3] = a.w;
            vs[b2][4] = b4.x; vs[b2][5] = b4.y; vs[b2][6] = b4.z; vs[b2][7] = b4.w;
        }
    }

    __syncthreads();   // the only barrier

    const int cbase = o * 16 + half * 8;   // + nn*512 + dd

    for (int nn = 0; nn < kNPerBlock; ++nn) {
        const int n = nchunk * kNPerBlock + nn;

        // x for my 4 b's — wave-uniform addresses -> scalar broadcast
        float xr[4][8];
#pragma unroll
        for (int b2 = 0; b2 < 4; ++b2) {
            const float* xp = xg + ((size_t)(bbase + b2) * kNi + n) * kDi;
#pragma unroll
            for (int i = 0; i < 8; ++i) xr[b2][i] = xp[i];
        }

        // x_hat: per dd one swizzled b128 W read, pipelined 3 deep
        float xh[4][8];
        int4 wr[8];
#pragma unroll
        for (int dd = 0; dd < 3; ++dd)
            wr[dd] = lds[swz(nn * kChunksPerN + cbase + dd)];
#pragma unroll
        for (int dd = 0; dd < 8; ++dd) {
            if (dd + 3 < 8)
                wr[dd + 3] = lds[swz(nn * kChunksPerN + cbase + dd + 3)];
            const int4 w = wr[dd];
            float wl[8];
            wl[0] = __uint_as_float(((unsigned)w.x) << 16);
            wl[1] = __uint_as_float(((unsigned)w.x) & 0xffff0000u);
            wl[2] = __uint_as_float(((unsigned)w.y) << 16);
            wl[3] = __uint_as_float(((unsigned)w.y) & 0xffff0000u);
            wl[4] = __uint_as_float(((unsigned)w.z) << 16);
            wl[5] = __uint_as_float(((unsigned)w.z) & 0xffff0000u);
            wl[6] = __uint_as_float(((unsigned)w.w) << 16);
            wl[7] = __uint_as_float(((unsigned)w.w) & 0xffff0000u);
#pragma unroll
            for (int b2 = 0; b2 < 4; ++b2) {
                float acc = 0.0f;
#pragma unroll
                for (int i = 0; i < 8; ++i)
                    acc = fmaf(xr[b2][i], wl[i], acc);
                xh[b2][dd] = acc;
            }
        }

        // coupling + accumulate
#pragma unroll
        for (int b2 = 0; b2 < 4; ++b2) {
            float c = 1.0f;
            if (PASS > 0) {
                float pl = 0.0f;
#pragma unroll
                for (int dd = 0; dd < 8; ++dd) pl = fmaf(vs[b2][dd], xh[b2][dd], pl);
                float L = pl + __shfl_xor(pl, 32);   // add other d-half
                float m = L;
#pragma unroll
                for (int msk = 16; msk >= 1; msk >>= 1)
                    m = fmaxf(m, __shfl_xor(m, msk));
                float e = __expf(L - m);
                float sm = e;
#pragma unroll
                for (int msk = 16; msk >= 1; msk >>= 1)
                    sm += __shfl_xor(sm, msk);
                c = e / sm;
            }
#pragma unroll
            for (int dd = 0; dd < 8; ++dd)
                sacc[b2][dd] = fmaf(c, xh[b2][dd], sacc[b2][dd]);
        }
    }

    // Flush: partial[b][chunk][od] bf16; my 8 od's contiguous -> int4 store.
#pragma unroll
    for (int b2 = 0; b2 < 4; ++b2) {
        int4 u;
        u.x = (int)pack_bf16(sacc[b2][0], sacc[b2][1]);
        u.y = (int)pack_bf16(sacc[b2][2], sacc[b2][3]);
        u.z = (int)pack_bf16(sacc[b2][4], sacc[b2][5]);
        u.w = (int)pack_bf16(sacc[b2][6], sacc[b2][7]);
        __hip_bfloat16* pp = partial
            + ((size_t)(bbase + b2) * kNBlocks + nchunk) * kSeg
            + o * kDo + half * 8;
        *reinterpret_cast<int4*>(pp) = u;   // 16 B aligned
    }
}

// ---------------------------------------------------------------------------
// Finish: sum partials over 256 chunks -> s[b,od]; squash; vsum / out.
// Grid 256 = (b x od-quarter), 128 threads, one od element per thread.
// ---------------------------------------------------------------------------
template<int PASS>
__global__ __launch_bounds__(128, 4)
void caps_finish(const __hip_bfloat16* __restrict__ partial,
                 float* __restrict__ vsum, float* __restrict__ out)
{
    const int b  = blockIdx.x >> 2;
    const int q  = blockIdx.x & 3;
    const int t  = threadIdx.x;
    const int od = q * 128 + t;

    const __hip_bfloat16* p = partial + (size_t)b * kNBlocks * kSeg + od;
    float s = 0.0f;
#pragma unroll 8
    for (int c = 0; c < kNBlocks; ++c)
        s += __bfloat162float(p[(size_t)c * kSeg]);
    if (PASS == 0) s *= (1.0f / 32.0f);   // uniform coupling 1/No

    __shared__ float sq[128];
    __shared__ float fo[8];
    sq[t] = s * s;
    __syncthreads();
    if (t < 8) {
        float n2 = 0.0f;
#pragma unroll
        for (int d = 0; d < 16; ++d) n2 += sq[t * 16 + d];
        fo[t] = sqrtf(n2) / (1.0f + n2);   // ||s|| / (1 + ||s||^2)
    }
    __syncthreads();

    const float v = fo[t >> 4] * s;

    if (PASS == 0)      vsum[(size_t)b * kSeg + od] = v;
    else if (PASS == 1) vsum[(size_t)b * kSeg + od] += v;
    else                out[(size_t)b * kSeg + od] = v;
}

// ---------------------------------------------------------------------------
extern "C" void kernel_launch(void* const* d_in, const int* in_sizes, int n_in,
                              void* d_out, int out_size, void* d_ws, size_t ws_size,
                              hipStream_t stream)
{
    const float* x = (const float*)d_in[0];   // (64, 2048, 8)
    const float* W = (const float*)d_in[1];   // (2048, 32, 16, 8)
    float* out = (float*)d_out;               // (64, 32, 16)

    // ws: bf16 partial [64][256][512] = 16.78 MB, then f32 vsum [64][512]
    __hip_bfloat16* partial = (__hip_bfloat16*)d_ws;
    float* vsum = (float*)((char*)d_ws
                  + (size_t)kB * kNBlocks * kSeg * sizeof(__hip_bfloat16));

    const dim3 gp(kNBlocks), bp(kThreads);
    const dim3 gf(kB * 4), bf(128);

    caps_pass<0><<<gp, bp, 0, stream>>>(x, W, vsum, partial);
    caps_finish<0><<<gf, bf, 0, stream>>>(partial, vsum, out);
    caps_pass<1><<<gp, bp, 0, stream>>>(x, W, vsum, partial);
    caps_finish<1><<<gf, bf, 0, stream>>>(partial, vsum, out);
    caps_pass<2><<<gp, bp, 0, stream>>>(x, W, vsum, partial);
    caps_finish<2><<<gf, bf, 0, stream>>>(partial, vsum, out);
}

// Round 7
// 129.968 us; speedup vs baseline: 1.0780x; 1.0780x over previous
//
#include <hip/hip_runtime.h>
#include <hip/hip_bf16.h>
#include <math.h>

// Problem constants
namespace {
constexpr int kB  = 64;
constexpr int kNi = 2048;
constexpr int kDi = 8;
constexpr int kNo = 32;
constexpr int kDo = 16;

constexpr int kThreads    = 512;                 // 8 waves
constexpr int kNSlabs     = 256;                 // n-slabs of 8 n
constexpr int kNPerBlock  = 8;
constexpr int kSeg        = kNo * kDo;           // 512 od elements
constexpr int kChunksPerN = 512;                 // 16B bf16 chunks per n
}

__device__ __forceinline__ unsigned pack_bf16(float lo, float hi) {
    union { __hip_bfloat162 h; unsigned u; } v;
    v.h = __float22bfloat162_rn(make_float2(lo, hi));
    return v.u;
}
__device__ __forceinline__ int swz(int c) { return c ^ ((c >> 4) & 7); }

__device__ __forceinline__ void unpack8(const int4 w, float* wl) {
    wl[0] = __uint_as_float(((unsigned)w.x) << 16);
    wl[1] = __uint_as_float(((unsigned)w.x) & 0xffff0000u);
    wl[2] = __uint_as_float(((unsigned)w.y) << 16);
    wl[3] = __uint_as_float(((unsigned)w.y) & 0xffff0000u);
    wl[4] = __uint_as_float(((unsigned)w.z) << 16);
    wl[5] = __uint_as_float(((unsigned)w.z) & 0xffff0000u);
    wl[6] = __uint_as_float(((unsigned)w.w) << 16);
    wl[7] = __uint_as_float(((unsigned)w.w) & 0xffff0000u);
}

// ---------------------------------------------------------------------------
// Pass kernel. Grid 512 = 256 n-slabs x 2 b-groups; 8 waves; wave owns 4 b's
// (bg*32 + wv*4 ..+4). W slab (8 n) staged once as packed bf16 = 64 KB LDS,
// one barrier; 2 blocks/CU co-resident -> 4 waves/SIMD.
// lane -> (o = lane&31, half = lane>>5 covering d in [half*8, half*8+8)).
// Per (n, dd): one swizzled ds_read_b128 = W[n,o,half*8+dd,0..8) bf16.
// Softmax over o WITHOUT max-subtraction (logits provably bounded |L| <~ 4):
// 1 cross-half shuffle + exp2 + 5-step sum butterfly + rcp. vsum pre-scaled
// by log2(e) so exp2 is direct.
// __launch_bounds__(512,2): 128-VGPR cap (empirical: arg2 = min blocks/CU;
// 1024-thread blocks snap to 64 VGPR and spill -> never use them).
// ---------------------------------------------------------------------------
template<int PASS>
__global__ __launch_bounds__(kThreads, 2)
void caps_pass(const float* __restrict__ xg, const float* __restrict__ Wg,
               const float* __restrict__ vsum, __hip_bfloat16* __restrict__ partial)
{
    __shared__ int4 lds[kNPerBlock * kChunksPerN];   // 65536 B

    const int tid    = threadIdx.x;
    const int nchunk = blockIdx.x & (kNSlabs - 1);   // 0..255
    const int bg     = blockIdx.x >> 8;              // 0..1
    const int wv     = __builtin_amdgcn_readfirstlane(tid >> 6);  // 0..7
    const int lane   = tid & 63;
    const int o      = lane & 31;
    const int half   = lane >> 5;
    const int bbase  = bg * 32 + wv * 4;             // 4 b's per wave

    // ---- stage 8 W tiles as packed bf16 (64 KB), swizzled ----
    {
        const float4* src = reinterpret_cast<const float4*>(Wg)
                          + (size_t)nchunk * (kNPerBlock * kChunksPerN * 2);
#pragma unroll
        for (int k = 0; k < (kNPerBlock * kChunksPerN) / kThreads; ++k) {  // 8
            int c = k * kThreads + tid;
            float4 a = src[2 * c], b = src[2 * c + 1];
            int4 u;
            u.x = (int)pack_bf16(a.x, a.y);
            u.y = (int)pack_bf16(a.z, a.w);
            u.z = (int)pack_bf16(b.x, b.y);
            u.w = (int)pack_bf16(b.z, b.w);
            lds[swz(c)] = u;
        }
    }

    float vs[4][8];
    float sacc[4][8];
#pragma unroll
    for (int b2 = 0; b2 < 4; ++b2) {
#pragma unroll
        for (int j = 0; j < 8; ++j) sacc[b2][j] = 0.0f;
        if (PASS > 0) {
            const float4* vp = reinterpret_cast<const float4*>(
                vsum + (size_t)(bbase + b2) * kSeg + o * kDo + half * 8);
            float4 a = vp[0], b4 = vp[1];
            const float lg2e = 1.44269504f;          // logits -> log2 domain
            vs[b2][0] = a.x * lg2e;  vs[b2][1] = a.y * lg2e;
            vs[b2][2] = a.z * lg2e;  vs[b2][3] = a.w * lg2e;
            vs[b2][4] = b4.x * lg2e; vs[b2][5] = b4.y * lg2e;
            vs[b2][6] = b4.z * lg2e; vs[b2][7] = b4.w * lg2e;
        }
    }

    __syncthreads();   // the only barrier

    const int cbase = o * 16 + half * 8;   // + nn*512 + dd

    for (int nn = 0; nn < kNPerBlock; ++nn) {
        const int n = nchunk * kNPerBlock + nn;

        // x for my 4 b's — wave-uniform addresses -> scalar broadcast (SGPRs)
        float xr[4][8];
#pragma unroll
        for (int b2 = 0; b2 < 4; ++b2) {
            const float* xp = xg + ((size_t)(bbase + b2) * kNi + n) * kDi;
#pragma unroll
            for (int i = 0; i < 8; ++i) xr[b2][i] = xp[i];
        }

        // x_hat: dd in pairs -> peak live regs = wr(8) + wl(16) + xh(32)
        float xh[4][8];
#pragma unroll
        for (int dp = 0; dp < 4; ++dp) {
            const int4 w0 = lds[swz(nn * kChunksPerN + cbase + 2 * dp + 0)];
            const int4 w1 = lds[swz(nn * kChunksPerN + cbase + 2 * dp + 1)];
            float wl0[8], wl1[8];
            unpack8(w0, wl0);
            unpack8(w1, wl1);
#pragma unroll
            for (int b2 = 0; b2 < 4; ++b2) {
                float a0 = 0.0f, a1 = 0.0f;
#pragma unroll
                for (int i = 0; i < 8; ++i) {
                    a0 = fmaf(xr[b2][i], wl0[i], a0);
                    a1 = fmaf(xr[b2][i], wl1[i], a1);
                }
                xh[b2][2 * dp + 0] = a0;
                xh[b2][2 * dp + 1] = a1;
            }
        }

        // coupling + accumulate (no-max softmax; logits bounded)
#pragma unroll
        for (int b2 = 0; b2 < 4; ++b2) {
            float c = 1.0f;
            if (PASS > 0) {
                float pl = 0.0f;
#pragma unroll
                for (int dd = 0; dd < 8; ++dd) pl = fmaf(vs[b2][dd], xh[b2][dd], pl);
                float L = pl + __shfl_xor(pl, 32);   // add other d-half (log2 dom.)
                float e = exp2f(L);
                float sm = e;
#pragma unroll
                for (int msk = 16; msk >= 1; msk >>= 1)
                    sm += __shfl_xor(sm, msk);
                c = e * __builtin_amdgcn_rcpf(sm);
            }
#pragma unroll
            for (int dd = 0; dd < 8; ++dd)
                sacc[b2][dd] = fmaf(c, xh[b2][dd], sacc[b2][dd]);
        }
    }

    // Flush: partial[b][chunk][od] bf16; my 8 od's contiguous -> int4 store.
#pragma unroll
    for (int b2 = 0; b2 < 4; ++b2) {
        int4 u;
        u.x = (int)pack_bf16(sacc[b2][0], sacc[b2][1]);
        u.y = (int)pack_bf16(sacc[b2][2], sacc[b2][3]);
        u.z = (int)pack_bf16(sacc[b2][4], sacc[b2][5]);
        u.w = (int)pack_bf16(sacc[b2][6], sacc[b2][7]);
        __hip_bfloat16* pp = partial
            + ((size_t)(bbase + b2) * kNSlabs + nchunk) * kSeg
            + o * kDo + half * 8;
        *reinterpret_cast<int4*>(pp) = u;   // 16 B aligned
    }
}

// ---------------------------------------------------------------------------
// Finish: sum partials over 256 slabs -> s[b,od]; squash; vsum / out.
// Grid 256 = (b x od-quarter), 128 threads, one od element per thread.
// ---------------------------------------------------------------------------
template<int PASS>
__global__ __launch_bounds__(128, 4)
void caps_finish(const __hip_bfloat16* __restrict__ partial,
                 float* __restrict__ vsum, float* __restrict__ out)
{
    const int b  = blockIdx.x >> 2;
    const int q  = blockIdx.x & 3;
    const int t  = threadIdx.x;
    const int od = q * 128 + t;

    const __hip_bfloat16* p = partial + (size_t)b * kNSlabs * kSeg + od;
    float s = 0.0f;
#pragma unroll 8
    for (int c = 0; c < kNSlabs; ++c)
        s += __bfloat162float(p[(size_t)c * kSeg]);
    if (PASS == 0) s *= (1.0f / 32.0f);   // uniform coupling 1/No

    __shared__ float sq[128];
    __shared__ float fo[8];
    sq[t] = s * s;
    __syncthreads();
    if (t < 8) {
        float n2 = 0.0f;
#pragma unroll
        for (int d = 0; d < 16; ++d) n2 += sq[t * 16 + d];
        fo[t] = sqrtf(n2) / (1.0f + n2);   // ||s|| / (1 + ||s||^2)
    }
    __syncthreads();

    const float v = fo[t >> 4] * s;

    if (PASS == 0)      vsum[(size_t)b * kSeg + od] = v;
    else if (PASS == 1) vsum[(size_t)b * kSeg + od] += v;
    else                out[(size_t)b * kSeg + od] = v;
}

// ---------------------------------------------------------------------------
extern "C" void kernel_launch(void* const* d_in, const int* in_sizes, int n_in,
                              void* d_out, int out_size, void* d_ws, size_t ws_size,
                              hipStream_t stream)
{
    const float* x = (const float*)d_in[0];   // (64, 2048, 8)
    const float* W = (const float*)d_in[1];   // (2048, 32, 16, 8)
    float* out = (float*)d_out;               // (64, 32, 16)

    // ws: bf16 partial [64][256][512] = 16.78 MB, then f32 vsum [64][512]
    __hip_bfloat16* partial = (__hip_bfloat16*)d_ws;
    float* vsum = (float*)((char*)d_ws
                  + (size_t)kB * kNSlabs * kSeg * sizeof(__hip_bfloat16));

    const dim3 gp(kNSlabs * 2), bp(kThreads);
    const dim3 gf(kB * 4), bf(128);

    caps_pass<0><<<gp, bp, 0, stream>>>(x, W, vsum, partial);
    caps_finish<0><<<gf, bf, 0, stream>>>(partial, vsum, out);
    caps_pass<1><<<gp, bp, 0, stream>>>(x, W, vsum, partial);
    caps_finish<1><<<gf, bf, 0, stream>>>(partial, vsum, out);
    caps_pass<2><<<gp, bp, 0, stream>>>(x, W, vsum, partial);
    caps_finish<2><<<gf, bf, 0, stream>>>(partial, vsum, out);
}

// Round 8
// 111.945 us; speedup vs baseline: 1.2515x; 1.1610x over previous
//
#include <hip/hip_runtime.h>
#include <hip/hip_bf16.h>
#include <math.h>

namespace {
constexpr int kB  = 64;
constexpr int kNi = 2048;
constexpr int kNo = 32;
constexpr int kDo = 16;
constexpr int kSeg    = kNo * kDo;      // 512 od
constexpr int kBlocks = 256;            // n-slabs (grid)
constexpr int kNPer   = kNi / kBlocks;  // 8 n per block
}

typedef __attribute__((ext_vector_type(4)))  short s4;    // 4 bf16 (2 VGPR)
typedef __attribute__((ext_vector_type(16))) float f16v;  // MFMA C/D

__device__ __forceinline__ f16v mfma_32x32x8_bf16(s4 a, s4 b, f16v c) {
#if __has_builtin(__builtin_amdgcn_mfma_f32_32x32x8bf16_1k)
    return __builtin_amdgcn_mfma_f32_32x32x8bf16_1k(a, b, c, 0, 0, 0);
#else
    asm("v_mfma_f32_32x32x8_bf16 %0, %1, %2, %0" : "+v"(c) : "v"(a), "v"(b));
    return c;
#endif
}

__device__ __forceinline__ unsigned pack_bf16(float lo, float hi) {
    union { __hip_bfloat162 h; unsigned u; } v;
    v.h = __float22bfloat162_rn(make_float2(lo, hi));
    return v.u;
}

// ---------------------------------------------------------------------------
// Prep: pack W and x into 32x32x8 MFMA fragment order, bf16.
// A-frag (W): wPack[((n*16+mt)*64+l)*4 + j] = W[n][mt*32+(l&31)][4*(l>>5)+j]
// B-frag (x): xPack[((n*2+nt)*64+l)*4 + j] = x[nt*32+(l&31)][n][4*(l>>5)+j]
// (k-map must only match between A and B — any bijective relabel cancels.)
// ---------------------------------------------------------------------------
__global__ __launch_bounds__(256, 4)
void caps_prep(const float* __restrict__ xg, const float* __restrict__ Wg,
               unsigned* __restrict__ wPack, unsigned* __restrict__ xPack)
{
    const int t = blockIdx.x * 256 + threadIdx.x;
    const int nW = kNi * 16 * 64;                  // 2,097,152 frag-lanes
    if (t < nW) {
        const int n = t >> 10, rem = t & 1023, mt = rem >> 6, l = rem & 63;
        const float4 w = *reinterpret_cast<const float4*>(
            Wg + ((size_t)n * kSeg + mt * 32 + (l & 31)) * 8 + 4 * (l >> 5));
        wPack[(size_t)t * 2 + 0] = pack_bf16(w.x, w.y);
        wPack[(size_t)t * 2 + 1] = pack_bf16(w.z, w.w);
    } else {
        const int t2 = t - nW;                     // < 2048*2*64 = 262,144
        const int n = t2 >> 7, rem = t2 & 127, nt = rem >> 6, l = rem & 63;
        const float4 v = *reinterpret_cast<const float4*>(
            xg + ((size_t)(nt * 32 + (l & 31)) * kNi + n) * 8 + 4 * (l >> 5));
        xPack[(size_t)t2 * 2 + 0] = pack_bf16(v.x, v.y);
        xPack[(size_t)t2 * 2 + 1] = pack_bf16(v.z, v.w);
    }
}

// C/D layout (m74/m101-verified for 32x32 MFMA on gfx950):
//   col = l&31 (= b), row = (reg&3) + 8*(reg>>2) + 4*(l>>5) (= od within tile)
// regs 0-7 -> o_local 0 (8 of its 16 d), regs 8-15 -> o_local 1; the other 8 d
// live in the partner lane l^32.

// ---------------------------------------------------------------------------
// Pass 0: s0[od,b] = sum_n x_hat (uniform coupling, 1/32 applied in finish).
// Pure MFMA accumulation over n. Grid 256 (8 n each), 8 waves = 4 mtq x 2 nt.
// ---------------------------------------------------------------------------
__global__ __launch_bounds__(512, 2)
void caps_pass0(const unsigned* __restrict__ wPack, const unsigned* __restrict__ xPack,
                __hip_bfloat16* __restrict__ partial)
{
    const int blk = blockIdx.x, tid = threadIdx.x;
    const int w   = __builtin_amdgcn_readfirstlane(tid >> 6);
    const int l   = tid & 63;
    const int mtq = w & 3, nt = w >> 2;
    const int b   = nt * 32 + (l & 31), hi = l >> 5;

    f16v acc[4];
#pragma unroll
    for (int m = 0; m < 4; ++m)
#pragma unroll
        for (int r = 0; r < 16; ++r) acc[m][r] = 0.0f;

    for (int nn = 0; nn < kNPer; ++nn) {
        const int n = blk * kNPer + nn;
        const s4 bfrag = *reinterpret_cast<const s4*>(
            xPack + ((size_t)(n * 2 + nt) * 64 + l) * 2);
#pragma unroll
        for (int m = 0; m < 4; ++m) {
            const int mt = mtq * 4 + m;
            const s4 afrag = *reinterpret_cast<const s4*>(
                wPack + ((size_t)(n * 16 + mt) * 64 + l) * 2);
            acc[m] = mfma_32x32x8_bf16(afrag, bfrag, acc[m]);
        }
    }

    // partial layout [slab][b][od] bf16; per quad: 4 consecutive od -> uint2
#pragma unroll
    for (int m = 0; m < 4; ++m) {
        const int mt = mtq * 4 + m;
#pragma unroll
        for (int q = 0; q < 4; ++q) {
            const int od = mt * 32 + 8 * q + 4 * hi;
            uint2 u;
            u.x = pack_bf16(acc[m][4 * q + 0], acc[m][4 * q + 1]);
            u.y = pack_bf16(acc[m][4 * q + 2], acc[m][4 * q + 3]);
            *reinterpret_cast<uint2*>(
                partial + ((size_t)blk * kB + b) * kSeg + od) = u;
        }
    }
}

// ---------------------------------------------------------------------------
// Routing pass (iters 1,2): two sweeps.
//  Phase 1: per (n): recompute x_hat tiles via MFMA, L = sum_d vsum*x_hat
//           (8 in-register FMA + 1 shfl_xor(32) per o), Z += exp2(L) over the
//           wave's 8 o's; cross-wave (4 mtq) LDS reduce -> R[nn][b] = 1/Z.
//  Phase 2: recompute tiles again, c = exp2(L)*R, sacc += c*x_hat.
// vsumPack is vsum pre-scaled by log2(e) in C-fragment row order.
// ---------------------------------------------------------------------------
__global__ __launch_bounds__(512, 1)
void caps_route(const unsigned* __restrict__ wPack, const unsigned* __restrict__ xPack,
                const float* __restrict__ vsumPack, __hip_bfloat16* __restrict__ partial)
{
    __shared__ float Zl[8][kNPer][32];
    __shared__ float Rl[kNPer][64];

    const int blk = blockIdx.x, tid = threadIdx.x;
    const int w   = __builtin_amdgcn_readfirstlane(tid >> 6);
    const int l   = tid & 63;
    const int mtq = w & 3, nt = w >> 2;
    const int b   = nt * 32 + (l & 31), hi = l >> 5;

    // vsum fragment: 16 f32 per mt (matches C rows), held in regs
    float vsp[4][16];
#pragma unroll
    for (int m = 0; m < 4; ++m) {
        const int mt = mtq * 4 + m;
        const float4* vp = reinterpret_cast<const float4*>(
            vsumPack + (((size_t)mt * 2 + hi) * 64 + b) * 16);
#pragma unroll
        for (int k = 0; k < 4; ++k) {
            const float4 v = vp[k];
            vsp[m][4 * k + 0] = v.x; vsp[m][4 * k + 1] = v.y;
            vsp[m][4 * k + 2] = v.z; vsp[m][4 * k + 3] = v.w;
        }
    }

    // ---- phase 1: Z ----
    float Zp[kNPer];
    for (int nn = 0; nn < kNPer; ++nn) {
        const int n = blk * kNPer + nn;
        const s4 bfrag = *reinterpret_cast<const s4*>(
            xPack + ((size_t)(n * 2 + nt) * 64 + l) * 2);
        float z = 0.0f;
#pragma unroll
        for (int m = 0; m < 4; ++m) {
            const int mt = mtq * 4 + m;
            const s4 afrag = *reinterpret_cast<const s4*>(
                wPack + ((size_t)(n * 16 + mt) * 64 + l) * 2);
            f16v c;
#pragma unroll
            for (int r = 0; r < 16; ++r) c[r] = 0.0f;
            c = mfma_32x32x8_bf16(afrag, bfrag, c);
            float p0 = 0.0f, p1 = 0.0f;
#pragma unroll
            for (int r = 0; r < 8; ++r) {
                p0 = fmaf(vsp[m][r],     c[r],     p0);
                p1 = fmaf(vsp[m][8 + r], c[8 + r], p1);
            }
            p0 += __shfl_xor(p0, 32);   // other 8 d's (partner hi-half)
            p1 += __shfl_xor(p1, 32);
            z += exp2f(p0) + exp2f(p1);
        }
        Zp[nn] = z;
    }
    if (l < 32) {
#pragma unroll
        for (int nn = 0; nn < kNPer; ++nn) Zl[w][nn][l] = Zp[nn];
    }
    __syncthreads();
    {
        const int ntr = tid >> 8, nn = (tid >> 5) & 7, b32 = tid & 31;
        const float z = Zl[ntr * 4 + 0][nn][b32] + Zl[ntr * 4 + 1][nn][b32]
                      + Zl[ntr * 4 + 2][nn][b32] + Zl[ntr * 4 + 3][nn][b32];
        Rl[nn][ntr * 32 + b32] = 1.0f / z;
    }
    __syncthreads();

    // ---- phase 2: s accumulation ----
    float sacc[4][16];
#pragma unroll
    for (int m = 0; m < 4; ++m)
#pragma unroll
        for (int r = 0; r < 16; ++r) sacc[m][r] = 0.0f;

    for (int nn = 0; nn < kNPer; ++nn) {
        const int n = blk * kNPer + nn;
        const s4 bfrag = *reinterpret_cast<const s4*>(
            xPack + ((size_t)(n * 2 + nt) * 64 + l) * 2);
        const float rz = Rl[nn][b];
#pragma unroll
        for (int m = 0; m < 4; ++m) {
            const int mt = mtq * 4 + m;
            const s4 afrag = *reinterpret_cast<const s4*>(
                wPack + ((size_t)(n * 16 + mt) * 64 + l) * 2);
            f16v c;
#pragma unroll
            for (int r = 0; r < 16; ++r) c[r] = 0.0f;
            c = mfma_32x32x8_bf16(afrag, bfrag, c);
            float p0 = 0.0f, p1 = 0.0f;
#pragma unroll
            for (int r = 0; r < 8; ++r) {
                p0 = fmaf(vsp[m][r],     c[r],     p0);
                p1 = fmaf(vsp[m][8 + r], c[8 + r], p1);
            }
            p0 += __shfl_xor(p0, 32);
            p1 += __shfl_xor(p1, 32);
            const float c0 = exp2f(p0) * rz, c1 = exp2f(p1) * rz;
#pragma unroll
            for (int r = 0; r < 8; ++r) {
                sacc[m][r]     = fmaf(c0, c[r],     sacc[m][r]);
                sacc[m][8 + r] = fmaf(c1, c[8 + r], sacc[m][8 + r]);
            }
        }
    }

#pragma unroll
    for (int m = 0; m < 4; ++m) {
        const int mt = mtq * 4 + m;
#pragma unroll
        for (int q = 0; q < 4; ++q) {
            const int od = mt * 32 + 8 * q + 4 * hi;
            uint2 u;
            u.x = pack_bf16(sacc[m][4 * q + 0], sacc[m][4 * q + 1]);
            u.y = pack_bf16(sacc[m][4 * q + 2], sacc[m][4 * q + 3]);
            *reinterpret_cast<uint2*>(
                partial + ((size_t)blk * kB + b) * kSeg + od) = u;
        }
    }
}

// ---------------------------------------------------------------------------
// Finish: sum partials [slab][b][od] over 256 slabs -> s; squash; update
// vsum (+ vsumPack in C-fragment row order, pre-scaled by log2 e) / out.
// ---------------------------------------------------------------------------
template<int PASS>
__global__ __launch_bounds__(128, 4)
void caps_finish(const __hip_bfloat16* __restrict__ partial,
                 float* __restrict__ vsum, float* __restrict__ vsumPack,
                 float* __restrict__ out)
{
    const int b  = blockIdx.x >> 2;
    const int q  = blockIdx.x & 3;
    const int t  = threadIdx.x;
    const int od = q * 128 + t;

    const __hip_bfloat16* p = partial + (size_t)b * kSeg + od;
    float s = 0.0f;
#pragma unroll 8
    for (int c = 0; c < kBlocks; ++c)
        s += __bfloat162float(p[(size_t)c * (kB * kSeg)]);
    if (PASS == 0) s *= (1.0f / 32.0f);   // uniform coupling 1/No

    __shared__ float sq[128];
    __shared__ float fo[8];
    sq[t] = s * s;
    __syncthreads();
    if (t < 8) {
        float n2 = 0.0f;
#pragma unroll
        for (int d = 0; d < 16; ++d) n2 += sq[t * 16 + d];
        fo[t] = sqrtf(n2) / (1.0f + n2);   // ||s|| / (1 + ||s||^2)
    }
    __syncthreads();

    const float v = fo[t >> 4] * s;

    float nv = v;
    if (PASS == 0) {
        vsum[(size_t)b * kSeg + od] = v;
    } else if (PASS == 1) {
        nv = vsum[(size_t)b * kSeg + od] + v;
        vsum[(size_t)b * kSeg + od] = nv;
    } else {
        out[(size_t)b * kSeg + od] = v;
    }
    if (PASS < 2) {
        // invert C-row map: row = (reg&3) + 8*(reg>>2) + 4*hi
        const int mt = od >> 5, r5 = od & 31;
        const int hi = (r5 >> 2) & 1, reg = (r5 & 3) | ((r5 >> 3) << 2);
        vsumPack[(((size_t)mt * 2 + hi) * 64 + b) * 16 + reg] = nv * 1.44269504f;
    }
}

// ---------------------------------------------------------------------------
extern "C" void kernel_launch(void* const* d_in, const int* in_sizes, int n_in,
                              void* d_out, int out_size, void* d_ws, size_t ws_size,
                              hipStream_t stream)
{
    const float* x = (const float*)d_in[0];   // (64, 2048, 8)
    const float* W = (const float*)d_in[1];   // (2048, 32, 16, 8)
    float* out = (float*)d_out;               // (64, 32, 16)

    // ws layout
    char* base = (char*)d_ws;
    __hip_bfloat16* partial = (__hip_bfloat16*)base;                  // 16.78 MB
    base += (size_t)kBlocks * kB * kSeg * sizeof(__hip_bfloat16);
    float* vsum = (float*)base;                                       // 128 KB
    base += (size_t)kB * kSeg * sizeof(float);
    float* vsumPack = (float*)base;                                   // 128 KB
    base += (size_t)16 * 2 * 64 * 16 * sizeof(float);
    unsigned* wPack = (unsigned*)base;                                // 16.78 MB
    base += (size_t)kNi * 16 * 64 * 2 * sizeof(unsigned);
    unsigned* xPack = (unsigned*)base;                                // 2 MB

    caps_prep<<<dim3(9216), dim3(256), 0, stream>>>(x, W, wPack, xPack);

    const dim3 gp(kBlocks), bp(512);
    const dim3 gf(kB * 4), bf(128);

    caps_pass0<<<gp, bp, 0, stream>>>(wPack, xPack, partial);
    caps_finish<0><<<gf, bf, 0, stream>>>(partial, vsum, vsumPack, out);
    caps_route<<<gp, bp, 0, stream>>>(wPack, xPack, vsumPack, partial);
    caps_finish<1><<<gf, bf, 0, stream>>>(partial, vsum, vsumPack, out);
    caps_route<<<gp, bp, 0, stream>>>(wPack, xPack, vsumPack, partial);
    caps_finish<2><<<gf, bf, 0, stream>>>(partial, vsum, vsumPack, out);
}

// Round 9
// 106.990 us; speedup vs baseline: 1.3095x; 1.0463x over previous
//
#include <hip/hip_runtime.h>
#include <hip/hip_bf16.h>
#include <math.h>

namespace {
constexpr int kB  = 64;
constexpr int kNi = 2048;
constexpr int kNo = 32;
constexpr int kDo = 16;
constexpr int kSeg    = kNo * kDo;      // 512 od
constexpr int kBlocks = 256;            // n-slabs (grid)
constexpr int kNPer   = kNi / kBlocks;  // 8 n per block
}

typedef __attribute__((ext_vector_type(4)))  short s4;    // 4 bf16 (2 VGPR)
typedef __attribute__((ext_vector_type(16))) float f16v;  // MFMA C/D

__device__ __forceinline__ f16v mfma_32x32x8_bf16(s4 a, s4 b, f16v c) {
#if __has_builtin(__builtin_amdgcn_mfma_f32_32x32x8bf16_1k)
    return __builtin_amdgcn_mfma_f32_32x32x8bf16_1k(a, b, c, 0, 0, 0);
#else
    asm("v_mfma_f32_32x32x8_bf16 %0, %1, %2, %0" : "+v"(c) : "v"(a), "v"(b));
    return c;
#endif
}

__device__ __forceinline__ unsigned pack_bf16(float lo, float hi) {
    union { __hip_bfloat162 h; unsigned u; } v;
    v.h = __float22bfloat162_rn(make_float2(lo, hi));
    return v.u;
}
__device__ __forceinline__ float bf_lo(unsigned u) {
    return __uint_as_float(u << 16);
}
__device__ __forceinline__ float bf_hi(unsigned u) {
    return __uint_as_float(u & 0xffff0000u);
}

// ---------------------------------------------------------------------------
// Prep: pack W and x into 32x32x8 MFMA fragment order, bf16.
// A-frag (W): wPack[((n*16+mt)*64+l)*4 + j] = W[n][mt*32+(l&31)][4*(l>>5)+j]
// B-frag (x): xPack[((n*2+nt)*64+l)*4 + j] = x[nt*32+(l&31)][n][4*(l>>5)+j]
// ---------------------------------------------------------------------------
__global__ __launch_bounds__(256, 4)
void caps_prep(const float* __restrict__ xg, const float* __restrict__ Wg,
               unsigned* __restrict__ wPack, unsigned* __restrict__ xPack)
{
    const int t = blockIdx.x * 256 + threadIdx.x;
    const int nW = kNi * 16 * 64;                  // 2,097,152 frag-lanes
    if (t < nW) {
        const int n = t >> 10, rem = t & 1023, mt = rem >> 6, l = rem & 63;
        const float4 w = *reinterpret_cast<const float4*>(
            Wg + ((size_t)n * kSeg + mt * 32 + (l & 31)) * 8 + 4 * (l >> 5));
        wPack[(size_t)t * 2 + 0] = pack_bf16(w.x, w.y);
        wPack[(size_t)t * 2 + 1] = pack_bf16(w.z, w.w);
    } else {
        const int t2 = t - nW;                     // < 2048*2*64 = 262,144
        const int n = t2 >> 7, rem = t2 & 127, nt = rem >> 6, l = rem & 63;
        const float4 v = *reinterpret_cast<const float4*>(
            xg + ((size_t)(nt * 32 + (l & 31)) * kNi + n) * 8 + 4 * (l >> 5));
        xPack[(size_t)t2 * 2 + 0] = pack_bf16(v.x, v.y);
        xPack[(size_t)t2 * 2 + 1] = pack_bf16(v.z, v.w);
    }
}

// C/D layout (m74/m101-verified): col = l&31 (= b),
// row = (reg&3) + 8*(reg>>2) + 4*(l>>5) (= od within 32-row tile).

// ---------------------------------------------------------------------------
// Pass 0: s0[od,b] = sum_n x_hat (uniform coupling; 1/32 applied in finish).
// ---------------------------------------------------------------------------
__global__ __launch_bounds__(512, 2)
void caps_pass0(const unsigned* __restrict__ wPack, const unsigned* __restrict__ xPack,
                __hip_bfloat16* __restrict__ partial)
{
    const int blk = blockIdx.x, tid = threadIdx.x;
    const int w   = __builtin_amdgcn_readfirstlane(tid >> 6);
    const int l   = tid & 63;
    const int mtq = w & 3, nt = w >> 2;
    const int b   = nt * 32 + (l & 31), hi = l >> 5;

    f16v acc[4];
#pragma unroll
    for (int m = 0; m < 4; ++m)
#pragma unroll
        for (int r = 0; r < 16; ++r) acc[m][r] = 0.0f;

    for (int nn = 0; nn < kNPer; ++nn) {
        const int n = blk * kNPer + nn;
        const s4 bfrag = *reinterpret_cast<const s4*>(
            xPack + ((size_t)(n * 2 + nt) * 64 + l) * 2);
#pragma unroll
        for (int m = 0; m < 4; ++m) {
            const int mt = mtq * 4 + m;
            const s4 afrag = *reinterpret_cast<const s4*>(
                wPack + ((size_t)(n * 16 + mt) * 64 + l) * 2);
            acc[m] = mfma_32x32x8_bf16(afrag, bfrag, acc[m]);
        }
    }

#pragma unroll
    for (int m = 0; m < 4; ++m) {
        const int mt = mtq * 4 + m;
#pragma unroll
        for (int q = 0; q < 4; ++q) {
            const int od = mt * 32 + 8 * q + 4 * hi;
            uint2 u;
            u.x = pack_bf16(acc[m][4 * q + 0], acc[m][4 * q + 1]);
            u.y = pack_bf16(acc[m][4 * q + 2], acc[m][4 * q + 3]);
            *reinterpret_cast<uint2*>(
                partial + ((size_t)blk * kB + b) * kSeg + od) = u;
        }
    }
}

// ---------------------------------------------------------------------------
// Routing pass (iters 1,2). All W/x fragments register-resident (loaded once).
// Phase 1: per (nn,m): MFMA tile, logit halves via pairwise FMA tree +
//   shfl_xor(32), e = exp2(L) stashed as packed bf16; Z summed from the
//   bf16-rounded e's (keeps sum_o c == 1 exact); cross-wave LDS reduce -> 1/Z.
// Phase 2: MFMA recompute from regs, c = e * rz, accumulate sacc. No loads.
// vsumPack is vsum pre-scaled by log2(e) in C-fragment row order.
// ---------------------------------------------------------------------------
__global__ __launch_bounds__(512, 1)
void caps_route(const unsigned* __restrict__ wPack, const unsigned* __restrict__ xPack,
                const float* __restrict__ vsumPack, __hip_bfloat16* __restrict__ partial)
{
    __shared__ float Zl[8][kNPer][32];
    __shared__ float Rl[kNPer][64];

    const int blk = blockIdx.x, tid = threadIdx.x;
    const int w   = __builtin_amdgcn_readfirstlane(tid >> 6);
    const int l   = tid & 63;
    const int mtq = w & 3, nt = w >> 2;
    const int b   = nt * 32 + (l & 31), hi = l >> 5;

    // ---- all fragments up front: afr 64 VGPR, bfr 16 VGPR ----
    s4 afr[kNPer][4];
    s4 bfr[kNPer];
#pragma unroll
    for (int nn = 0; nn < kNPer; ++nn) {
        const int n = blk * kNPer + nn;
        bfr[nn] = *reinterpret_cast<const s4*>(
            xPack + ((size_t)(n * 2 + nt) * 64 + l) * 2);
#pragma unroll
        for (int m = 0; m < 4; ++m) {
            const int mt = mtq * 4 + m;
            afr[nn][m] = *reinterpret_cast<const s4*>(
                wPack + ((size_t)(n * 16 + mt) * 64 + l) * 2);
        }
    }

    // vsum fragment (16 f32 per mt, C-row order)
    float vsp[4][16];
#pragma unroll
    for (int m = 0; m < 4; ++m) {
        const int mt = mtq * 4 + m;
        const float4* vp = reinterpret_cast<const float4*>(
            vsumPack + (((size_t)mt * 2 + hi) * 64 + b) * 16);
#pragma unroll
        for (int k = 0; k < 4; ++k) {
            const float4 v = vp[k];
            vsp[m][4 * k + 0] = v.x; vsp[m][4 * k + 1] = v.y;
            vsp[m][4 * k + 2] = v.z; vsp[m][4 * k + 3] = v.w;
        }
    }

    // ---- phase 1: logits, e-stash (packed bf16), Z ----
    unsigned est[kNPer][4];
#pragma unroll
    for (int nn = 0; nn < kNPer; ++nn) {
        float z = 0.0f;
#pragma unroll
        for (int m = 0; m < 4; ++m) {
            f16v c;
#pragma unroll
            for (int r = 0; r < 16; ++r) c[r] = 0.0f;
            c = mfma_32x32x8_bf16(afr[nn][m], bfr[nn], c);
            // pairwise logit tree (halves chain depth vs 8-deep fmaf chain)
            float a0 = fmaf(vsp[m][1], c[1], vsp[m][0] * c[0]);
            float a1 = fmaf(vsp[m][3], c[3], vsp[m][2] * c[2]);
            float a2 = fmaf(vsp[m][5], c[5], vsp[m][4] * c[4]);
            float a3 = fmaf(vsp[m][7], c[7], vsp[m][6] * c[6]);
            float p0 = (a0 + a1) + (a2 + a3);
            float b0 = fmaf(vsp[m][9],  c[9],  vsp[m][8]  * c[8]);
            float b1 = fmaf(vsp[m][11], c[11], vsp[m][10] * c[10]);
            float b2 = fmaf(vsp[m][13], c[13], vsp[m][12] * c[12]);
            float b3 = fmaf(vsp[m][15], c[15], vsp[m][14] * c[14]);
            float p1 = (b0 + b1) + (b2 + b3);
            p0 += __shfl_xor(p0, 32);   // partner half's 8 d's
            p1 += __shfl_xor(p1, 32);
            const unsigned u = pack_bf16(exp2f(p0), exp2f(p1));
            est[nn][m] = u;
            z += bf_lo(u) + bf_hi(u);   // Z from rounded e's: sum_o c == 1
        }
        if (l < 32) Zl[w][nn][l] = z;
    }
    __syncthreads();
    {
        const int ntr = tid >> 8, nn = (tid >> 5) & 7, b32 = tid & 31;
        const float z = Zl[ntr * 4 + 0][nn][b32] + Zl[ntr * 4 + 1][nn][b32]
                      + Zl[ntr * 4 + 2][nn][b32] + Zl[ntr * 4 + 3][nn][b32];
        Rl[nn][ntr * 32 + b32] = 1.0f / z;
    }
    __syncthreads();

    // ---- phase 2: sacc accumulation (register-only inputs) ----
    float sacc[4][16];
#pragma unroll
    for (int m = 0; m < 4; ++m)
#pragma unroll
        for (int r = 0; r < 16; ++r) sacc[m][r] = 0.0f;

#pragma unroll
    for (int nn = 0; nn < kNPer; ++nn) {
        const float rz = Rl[nn][b];
#pragma unroll
        for (int m = 0; m < 4; ++m) {
            f16v c;
#pragma unroll
            for (int r = 0; r < 16; ++r) c[r] = 0.0f;
            c = mfma_32x32x8_bf16(afr[nn][m], bfr[nn], c);
            const unsigned u = est[nn][m];
            const float c0 = bf_lo(u) * rz, c1 = bf_hi(u) * rz;
#pragma unroll
            for (int r = 0; r < 8; ++r) {
                sacc[m][r]     = fmaf(c0, c[r],     sacc[m][r]);
                sacc[m][8 + r] = fmaf(c1, c[8 + r], sacc[m][8 + r]);
            }
        }
    }

#pragma unroll
    for (int m = 0; m < 4; ++m) {
        const int mt = mtq * 4 + m;
#pragma unroll
        for (int q = 0; q < 4; ++q) {
            const int od = mt * 32 + 8 * q + 4 * hi;
            uint2 u;
            u.x = pack_bf16(sacc[m][4 * q + 0], sacc[m][4 * q + 1]);
            u.y = pack_bf16(sacc[m][4 * q + 2], sacc[m][4 * q + 3]);
            *reinterpret_cast<uint2*>(
                partial + ((size_t)blk * kB + b) * kSeg + od) = u;
        }
    }
}

// ---------------------------------------------------------------------------
// Finish: sum partials [slab][b][od] over 256 slabs -> s; squash; update
// vsum (+ vsumPack, log2e-scaled, C-row order) / out.
// 512 threads = 4 slab-groups x 128 od lanes (4x memory parallelism).
// ---------------------------------------------------------------------------
template<int PASS>
__global__ __launch_bounds__(512, 2)
void caps_finish(const __hip_bfloat16* __restrict__ partial,
                 float* __restrict__ vsum, float* __restrict__ vsumPack,
                 float* __restrict__ out)
{
    const int b  = blockIdx.x >> 2;
    const int q  = blockIdx.x & 3;
    const int t  = threadIdx.x;
    const int tl = t & 127;
    const int cg = t >> 7;            // slab group 0..3 (64 slabs each)
    const int od = q * 128 + tl;

    const __hip_bfloat16* p = partial
        + ((size_t)(cg * 64) * kB + b) * kSeg + od;
    float s = 0.0f;
#pragma unroll 16
    for (int k = 0; k < 64; ++k)
        s += __bfloat162float(p[(size_t)k * (kB * kSeg)]);

    __shared__ float red[4][128];
    __shared__ float sq[128];
    __shared__ float fo[8];
    red[cg][tl] = s;
    __syncthreads();
    if (t < 128) {
        s = (red[0][tl] + red[1][tl]) + (red[2][tl] + red[3][tl]);
        if (PASS == 0) s *= (1.0f / 32.0f);   // uniform coupling 1/No
        sq[tl] = s * s;
    }
    __syncthreads();
    if (t < 8) {
        float n2 = 0.0f;
#pragma unroll
        for (int d = 0; d < 16; ++d) n2 += sq[t * 16 + d];
        fo[t] = sqrtf(n2) / (1.0f + n2);   // ||s|| / (1 + ||s||^2)
    }
    __syncthreads();
    if (t < 128) {
        const float v = fo[tl >> 4] * s;
        float nv = v;
        if (PASS == 0) {
            vsum[(size_t)b * kSeg + od] = v;
        } else if (PASS == 1) {
            nv = vsum[(size_t)b * kSeg + od] + v;
            vsum[(size_t)b * kSeg + od] = nv;
        } else {
            out[(size_t)b * kSeg + od] = v;
        }
        if (PASS < 2) {
            // invert C-row map: row = (reg&3) + 8*(reg>>2) + 4*hi
            const int mt = od >> 5, r5 = od & 31;
            const int hi = (r5 >> 2) & 1, reg = (r5 & 3) | ((r5 >> 3) << 2);
            vsumPack[(((size_t)mt * 2 + hi) * 64 + b) * 16 + reg] =
                nv * 1.44269504f;
        }
    }
}

// ---------------------------------------------------------------------------
extern "C" void kernel_launch(void* const* d_in, const int* in_sizes, int n_in,
                              void* d_out, int out_size, void* d_ws, size_t ws_size,
                              hipStream_t stream)
{
    const float* x = (const float*)d_in[0];   // (64, 2048, 8)
    const float* W = (const float*)d_in[1];   // (2048, 32, 16, 8)
    float* out = (float*)d_out;               // (64, 32, 16)

    // ws layout
    char* base = (char*)d_ws;
    __hip_bfloat16* partial = (__hip_bfloat16*)base;                  // 16.78 MB
    base += (size_t)kBlocks * kB * kSeg * sizeof(__hip_bfloat16);
    float* vsum = (float*)base;                                       // 128 KB
    base += (size_t)kB * kSeg * sizeof(float);
    float* vsumPack = (float*)base;                                   // 128 KB
    base += (size_t)16 * 2 * 64 * 16 * sizeof(float);
    unsigned* wPack = (unsigned*)base;                                // 16.78 MB
    base += (size_t)kNi * 16 * 64 * 2 * sizeof(unsigned);
    unsigned* xPack = (unsigned*)base;                                // 2 MB

    caps_prep<<<dim3(9216), dim3(256), 0, stream>>>(x, W, wPack, xPack);

    const dim3 gp(kBlocks), bp(512);
    const dim3 gf(kB * 4), bf(512);

    caps_pass0<<<gp, bp, 0, stream>>>(wPack, xPack, partial);
    caps_finish<0><<<gf, bf, 0, stream>>>(partial, vsum, vsumPack, out);
    caps_route<<<gp, bp, 0, stream>>>(wPack, xPack, vsumPack, partial);
    caps_finish<1><<<gf, bf, 0, stream>>>(partial, vsum, vsumPack, out);
    caps_route<<<gp, bp, 0, stream>>>(wPack, xPack, vsumPack, partial);
    caps_finish<2><<<gf, bf, 0, stream>>>(partial, vsum, vsumPack, out);
}